// Round 9
// baseline (18.134 us; speedup 1.0000x reference)
//
#include <hip/hip_runtime.h>

// PrimitiveCollisionCost: B=16 H=64 L=12 S=8 W=256, N = B*H = 1024
// One block (256 thr) per n.
// Phase 1: threads 0..95 compute world-frame centers (one per (l,s)) into LDS.
// Phase 2: wave w owns links 3w..3w+2; lane owns 4 world spheres in 2 packed
//          float2 slots (A={w,w+64}, B={w+128,w+192}); distance math in
//          packed fp32 (v_pk_fma_f32 etc.), sqrt on trans pipe per lane-slot.

#define NL 12
#define NS 8

typedef float v2f __attribute__((ext_vector_type(2)));

__device__ __forceinline__ float fast_sqrtf(float x) {
    return __builtin_amdgcn_sqrtf(x);   // single v_sqrt_f32 (~1 ulp)
}

__global__ __launch_bounds__(256) void pcc_kernel(
    const float* __restrict__ pos,    // (N, L, 3)
    const float* __restrict__ rot,    // (N, L, 9)
    const float* __restrict__ lsph,   // (L, S, 4)
    const float* __restrict__ wsph,   // (W, 4)
    const float* __restrict__ weight, // scalar
    float* __restrict__ out)          // (N)
{
    const int n    = blockIdx.x;
    const int tid  = threadIdx.x;
    const int lane = tid & 63;
    const int wave = tid >> 6;   // 0..3, wave w owns links 3w..3w+2

    __shared__ float4 cen[NL * NS];   // (cx, cy, cz, rob_r) per (l,s)
    __shared__ float partial[4];

    // ---- Phase 1: 96 threads compute 96 centers (once per block) ----
    if (tid < NL * NS) {
        const int l = tid >> 3;               // tid = l*8 + s
        const float* r = rot + ((size_t)n * NL + l) * 9;
        const float* p = pos + ((size_t)n * NL + l) * 3;
        const float4 ls = reinterpret_cast<const float4*>(lsph)[tid];
        const float cx = r[0]*ls.x + r[1]*ls.y + r[2]*ls.z + p[0];
        const float cy = r[3]*ls.x + r[4]*ls.y + r[5]*ls.z + p[1];
        const float cz = r[6]*ls.x + r[7]*ls.y + r[8]*ls.z + p[2];
        cen[tid] = make_float4(cx, cy, cz, ls.w);
    }

    // 4 world spheres per lane, packed into float2 slots (overlaps phase 1).
    const float4* wsph4 = reinterpret_cast<const float4*>(wsph);
    const float4 ws0 = wsph4[lane];
    const float4 ws1 = wsph4[lane + 64];
    const float4 ws2 = wsph4[lane + 128];
    const float4 ws3 = wsph4[lane + 192];
    const v2f wxA = {ws0.x, ws1.x}, wyA = {ws0.y, ws1.y}, wzA = {ws0.z, ws1.z}, wrA = {ws0.w, ws1.w};
    const v2f wxB = {ws2.x, ws3.x}, wyB = {ws2.y, ws3.y}, wzB = {ws2.z, ws3.z}, wrB = {ws2.w, ws3.w};

    __syncthreads();

    // ---- Phase 2: packed-fp32 distances, LDS broadcast centers ----
    float m[3];
    m[0] = m[1] = m[2] = -1e30f;
    const float4* base = &cen[wave * 24];

#pragma unroll
    for (int li = 0; li < 3; ++li) {
#pragma unroll
        for (int s = 0; s < NS; ++s) {
            const float4 c = base[li * NS + s];   // wave-uniform ds_read_b128
            const v2f cx = {c.x, c.x}, cy = {c.y, c.y}, cz = {c.z, c.z};

            const v2f dxA = cx - wxA, dyA = cy - wyA, dzA = cz - wzA;
            const v2f dxB = cx - wxB, dyB = cy - wyB, dzB = cz - wzB;

            const v2f d2A = __builtin_elementwise_fma(dzA, dzA,
                              __builtin_elementwise_fma(dyA, dyA, dxA * dxA));
            const v2f d2B = __builtin_elementwise_fma(dzB, dzB,
                              __builtin_elementwise_fma(dyB, dyB, dxB * dxB));

            const v2f distA = {fast_sqrtf(d2A.x), fast_sqrtf(d2A.y)};
            const v2f distB = {fast_sqrtf(d2B.x), fast_sqrtf(d2B.y)};

            const v2f gA = wrA - distA;           // w_r - dist  (rr added after max)
            const v2f gB = wrB - distB;

            const v2f t = __builtin_elementwise_max(gA, gB);
            const float tm = fmaxf(t.x, t.y);
            m[li] = fmaxf(m[li], tm + c.w);       // + rob_r once per center
        }
    }

    // Three interleaved 64-lane max butterflies.
#pragma unroll
    for (int off = 1; off < 64; off <<= 1) {
        m[0] = fmaxf(m[0], __shfl_xor(m[0], off));
        m[1] = fmaxf(m[1], __shfl_xor(m[1], off));
        m[2] = fmaxf(m[2], __shfl_xor(m[2], off));
    }

    // d = clip(m + 0.1, 0, 0.2) / 0.25  (== clamp * 4)
    const float acc = fminf(fmaxf(m[0] + 0.1f, 0.0f), 0.2f) * 4.0f
                    + fminf(fmaxf(m[1] + 0.1f, 0.0f), 0.2f) * 4.0f
                    + fminf(fmaxf(m[2] + 0.1f, 0.0f), 0.2f) * 4.0f;

    if (lane == 0) partial[wave] = acc;
    __syncthreads();
    if (tid == 0)
        out[n] = weight[0] * (partial[0] + partial[1] + partial[2] + partial[3]);
}

extern "C" void kernel_launch(void* const* d_in, const int* in_sizes, int n_in,
                              void* d_out, int out_size, void* d_ws, size_t ws_size,
                              hipStream_t stream) {
    const float* pos    = (const float*)d_in[0];
    const float* rot    = (const float*)d_in[1];
    const float* lsph   = (const float*)d_in[2];
    const float* wsph   = (const float*)d_in[3];
    const float* weight = (const float*)d_in[4];
    float* out = (float*)d_out;

    const int N = out_size; // 1024
    pcc_kernel<<<N, 256, 0, stream>>>(pos, rot, lsph, wsph, weight, out);
}

// Round 10
// 13.503 us; speedup vs baseline: 1.3430x; 1.3430x over previous
//
#include <hip/hip_runtime.h>

// PrimitiveCollisionCost: B=16 H=64 L=12 S=8 W=256, N = B*H = 1024
// One block (256 thr) per n.
// Phase 1: threads 0..95 compute world-frame centers (one per (l,s)) into LDS.
// Phase 2: wave w owns links 3w..3w+2 (24 centers); lane owns 4 world spheres
//          (registers). Distances read centers from LDS (wave-uniform broadcast).
// __launch_bounds__(256,4): cap VGPR<=128 so 4 blocks/CU stay resident
// (16 waves/CU) -- latency hiding at the grid-available occupancy.

#define NL 12
#define NS 8

__device__ __forceinline__ float fast_sqrtf(float x) {
    return __builtin_amdgcn_sqrtf(x);   // single v_sqrt_f32 (~1 ulp)
}

__global__ __launch_bounds__(256, 4) void pcc_kernel(
    const float* __restrict__ pos,    // (N, L, 3)
    const float* __restrict__ rot,    // (N, L, 9)
    const float* __restrict__ lsph,   // (L, S, 4)
    const float* __restrict__ wsph,   // (W, 4)
    const float* __restrict__ weight, // scalar
    float* __restrict__ out)          // (N)
{
    const int n    = blockIdx.x;
    const int tid  = threadIdx.x;
    const int lane = tid & 63;
    const int wave = tid >> 6;   // 0..3, wave w owns links 3w..3w+2

    __shared__ float4 cen[NL * NS];   // (cx, cy, cz, rob_r) per (l,s)
    __shared__ float partial[4];

    // ---- Phase 1: 96 threads compute 96 centers (once per block) ----
    if (tid < NL * NS) {
        const int l = tid >> 3;               // tid = l*8 + s
        const float* r = rot + ((size_t)n * NL + l) * 9;
        const float* p = pos + ((size_t)n * NL + l) * 3;
        const float4 ls = reinterpret_cast<const float4*>(lsph)[tid];
        const float cx = r[0]*ls.x + r[1]*ls.y + r[2]*ls.z + p[0];
        const float cy = r[3]*ls.x + r[4]*ls.y + r[5]*ls.z + p[1];
        const float cz = r[6]*ls.x + r[7]*ls.y + r[8]*ls.z + p[2];
        cen[tid] = make_float4(cx, cy, cz, ls.w);
    }

    // Each lane owns 4 world spheres, register-resident (overlaps phase 1).
    const float4* wsph4 = reinterpret_cast<const float4*>(wsph);
    const float4 ws0 = wsph4[lane];
    const float4 ws1 = wsph4[lane + 64];
    const float4 ws2 = wsph4[lane + 128];
    const float4 ws3 = wsph4[lane + 192];

    __syncthreads();

    // ---- Phase 2: pure LDS + VALU distance/max, 24 centers per wave ----
    float m[3];
    m[0] = m[1] = m[2] = -1e30f;
    const float4* base = &cen[wave * 24];

#pragma unroll
    for (int i = 0; i < 24; ++i) {
        const float4 c = base[i];             // wave-uniform ds_read_b128
        const float rr = c.w;

        const float dx0 = c.x - ws0.x, dy0 = c.y - ws0.y, dz0 = c.z - ws0.z;
        const float dx1 = c.x - ws1.x, dy1 = c.y - ws1.y, dz1 = c.z - ws1.z;
        const float dx2 = c.x - ws2.x, dy2 = c.y - ws2.y, dz2 = c.z - ws2.z;
        const float dx3 = c.x - ws3.x, dy3 = c.y - ws3.y, dz3 = c.z - ws3.z;

        const float v0 = ws0.w + rr - fast_sqrtf(dx0*dx0 + dy0*dy0 + dz0*dz0);
        const float v1 = ws1.w + rr - fast_sqrtf(dx1*dx1 + dy1*dy1 + dz1*dz1);
        const float v2 = ws2.w + rr - fast_sqrtf(dx2*dx2 + dy2*dy2 + dz2*dz2);
        const float v3 = ws3.w + rr - fast_sqrtf(dx3*dx3 + dy3*dy3 + dz3*dz3);

        const int li = i >> 3;                // compile-time after unroll
        m[li] = fmaxf(fmaxf(m[li], v0), v1);  // v_max3_f32
        m[li] = fmaxf(fmaxf(m[li], v2), v3);  // v_max3_f32
    }

    // Three interleaved 64-lane max butterflies.
#pragma unroll
    for (int off = 1; off < 64; off <<= 1) {
        m[0] = fmaxf(m[0], __shfl_xor(m[0], off));
        m[1] = fmaxf(m[1], __shfl_xor(m[1], off));
        m[2] = fmaxf(m[2], __shfl_xor(m[2], off));
    }

    // d = clip(m + 0.1, 0, 0.2) / 0.25  (== clamp * 4)
    const float acc = fminf(fmaxf(m[0] + 0.1f, 0.0f), 0.2f) * 4.0f
                    + fminf(fmaxf(m[1] + 0.1f, 0.0f), 0.2f) * 4.0f
                    + fminf(fmaxf(m[2] + 0.1f, 0.0f), 0.2f) * 4.0f;

    if (lane == 0) partial[wave] = acc;
    __syncthreads();
    if (tid == 0)
        out[n] = weight[0] * (partial[0] + partial[1] + partial[2] + partial[3]);
}

extern "C" void kernel_launch(void* const* d_in, const int* in_sizes, int n_in,
                              void* d_out, int out_size, void* d_ws, size_t ws_size,
                              hipStream_t stream) {
    const float* pos    = (const float*)d_in[0];
    const float* rot    = (const float*)d_in[1];
    const float* lsph   = (const float*)d_in[2];
    const float* wsph   = (const float*)d_in[3];
    const float* weight = (const float*)d_in[4];
    float* out = (float*)d_out;

    const int N = out_size; // 1024
    pcc_kernel<<<N, 256, 0, stream>>>(pos, rot, lsph, wsph, weight, out);
}

// Round 12
// 13.069 us; speedup vs baseline: 1.3876x; 1.0332x over previous
//
#include <hip/hip_runtime.h>

// PrimitiveCollisionCost: B=16 H=64 L=12 S=8 W=256, N = B*H = 1024
// One block (256 thr) per n.
// Phase 1: threads 0..95 compute world-frame centers; store coords DUPLICATED
//          ({cx,cx},{cy,cy},{cz,cz},{|c|2,|c|2}) so phase 2 reads VOP3P-ready
//          broadcast pairs straight from LDS (ds_read_b128 x2).
// Phase 2: wave w owns links 3w..3w+2; lane owns 4 world spheres packed as
//          2 pairs. dist^2 via quadratic form d2 = (|c|2+|w|2) - 2 c.w in
//          v_pk_add_f32 / v_pk_fma_f32 (pairs only -- no op_sel, no pk_max).

#define NL 12
#define NS 8

typedef float v2f __attribute__((ext_vector_type(2)));

__device__ __forceinline__ float fast_sqrtf(float x) {
    return __builtin_amdgcn_sqrtf(x);   // single v_sqrt_f32 (~1 ulp)
}

__device__ __forceinline__ v2f pk_add(v2f a, v2f b) {
    v2f d;
    asm("v_pk_add_f32 %0, %1, %2" : "=v"(d) : "v"(a), "v"(b));
    return d;
}
__device__ __forceinline__ void pk_fma(v2f& acc, v2f a, v2f b) {
    asm("v_pk_fma_f32 %0, %1, %2, %0" : "+v"(acc) : "v"(a), "v"(b));
}

struct alignas(16) Cen { v2f cx, cy, cz, c2; };   // 32 B, all halves duplicated

__global__ __launch_bounds__(256) void pcc_kernel(
    const float* __restrict__ pos,    // (N, L, 3)
    const float* __restrict__ rot,    // (N, L, 9)
    const float* __restrict__ lsph,   // (L, S, 4)
    const float* __restrict__ wsph,   // (W, 4)
    const float* __restrict__ weight, // scalar
    float* __restrict__ out)          // (N)
{
    const int n    = blockIdx.x;
    const int tid  = threadIdx.x;
    const int lane = tid & 63;
    const int wave = tid >> 6;   // 0..3, wave w owns links 3w..3w+2

    __shared__ Cen   cdup[NL * NS];
    __shared__ float rrs[NL * NS];
    __shared__ float partial[4];

    // ---- Phase 1: 96 threads compute 96 centers (once per block) ----
    if (tid < NL * NS) {
        const int l = tid >> 3;               // tid = l*8 + s
        const float* r = rot + ((size_t)n * NL + l) * 9;
        const float* p = pos + ((size_t)n * NL + l) * 3;
        const float4 ls = reinterpret_cast<const float4*>(lsph)[tid];
        const float cx = r[0]*ls.x + r[1]*ls.y + r[2]*ls.z + p[0];
        const float cy = r[3]*ls.x + r[4]*ls.y + r[5]*ls.z + p[1];
        const float cz = r[6]*ls.x + r[7]*ls.y + r[8]*ls.z + p[2];
        const float c2 = cx*cx + cy*cy + cz*cz;
        Cen c;
        c.cx = (v2f){cx, cx};
        c.cy = (v2f){cy, cy};
        c.cz = (v2f){cz, cz};
        c.c2 = (v2f){c2, c2};
        cdup[tid] = c;
        rrs[tid]  = ls.w;
    }

    // 4 world spheres per lane, packed as pairs A=(s0,s1), B=(s2,s3):
    // nw* = -2*w*, q = |w|^2.
    const float4* wsph4 = reinterpret_cast<const float4*>(wsph);
    const float4 ws0 = wsph4[lane];
    const float4 ws1 = wsph4[lane + 64];
    const float4 ws2 = wsph4[lane + 128];
    const float4 ws3 = wsph4[lane + 192];
    const v2f nwxA = {-2.f*ws0.x, -2.f*ws1.x}, nwyA = {-2.f*ws0.y, -2.f*ws1.y}, nwzA = {-2.f*ws0.z, -2.f*ws1.z};
    const v2f nwxB = {-2.f*ws2.x, -2.f*ws3.x}, nwyB = {-2.f*ws2.y, -2.f*ws3.y}, nwzB = {-2.f*ws2.z, -2.f*ws3.z};
    const v2f qA = {ws0.x*ws0.x + ws0.y*ws0.y + ws0.z*ws0.z,
                    ws1.x*ws1.x + ws1.y*ws1.y + ws1.z*ws1.z};
    const v2f qB = {ws2.x*ws2.x + ws2.y*ws2.y + ws2.z*ws2.z,
                    ws3.x*ws3.x + ws3.y*ws3.y + ws3.z*ws3.z};
    const float wr0 = ws0.w, wr1 = ws1.w, wr2 = ws2.w, wr3 = ws3.w;

    __syncthreads();

    // ---- Phase 2: packed quadratic-form distances ----
    float m[3];
    m[0] = m[1] = m[2] = -1e30f;
    const Cen*   base  = &cdup[wave * 24];
    const float* baser = &rrs[wave * 24];

#pragma unroll
    for (int i = 0; i < 24; ++i) {
        const Cen c = base[i];                // wave-uniform ds_read_b128 x2

        v2f dA = pk_add(qA, c.c2);            // |w|^2 + |c|^2
        v2f dB = pk_add(qB, c.c2);
        pk_fma(dA, c.cx, nwxA);               // - 2 c.w
        pk_fma(dB, c.cx, nwxB);
        pk_fma(dA, c.cy, nwyA);
        pk_fma(dB, c.cy, nwyB);
        pk_fma(dA, c.cz, nwzA);
        pk_fma(dB, c.cz, nwzB);

        const float g0 = wr0 - fast_sqrtf(fmaxf(dA.x, 0.0f));
        const float g1 = wr1 - fast_sqrtf(fmaxf(dA.y, 0.0f));
        const float g2 = wr2 - fast_sqrtf(fmaxf(dB.x, 0.0f));
        const float g3 = wr3 - fast_sqrtf(fmaxf(dB.y, 0.0f));

        const int li = i >> 3;                // compile-time after unroll
        m[li] = fmaxf(m[li], fmaxf(fmaxf(g0, g1), fmaxf(g2, g3)) + baser[i]);
    }

    // Three interleaved 64-lane max butterflies.
#pragma unroll
    for (int off = 1; off < 64; off <<= 1) {
        m[0] = fmaxf(m[0], __shfl_xor(m[0], off));
        m[1] = fmaxf(m[1], __shfl_xor(m[1], off));
        m[2] = fmaxf(m[2], __shfl_xor(m[2], off));
    }

    // d = clip(m + 0.1, 0, 0.2) / 0.25  (== clamp * 4)
    const float acc = fminf(fmaxf(m[0] + 0.1f, 0.0f), 0.2f) * 4.0f
                    + fminf(fmaxf(m[1] + 0.1f, 0.0f), 0.2f) * 4.0f
                    + fminf(fmaxf(m[2] + 0.1f, 0.0f), 0.2f) * 4.0f;

    if (lane == 0) partial[wave] = acc;
    __syncthreads();
    if (tid == 0)
        out[n] = weight[0] * (partial[0] + partial[1] + partial[2] + partial[3]);
}

extern "C" void kernel_launch(void* const* d_in, const int* in_sizes, int n_in,
                              void* d_out, int out_size, void* d_ws, size_t ws_size,
                              hipStream_t stream) {
    const float* pos    = (const float*)d_in[0];
    const float* rot    = (const float*)d_in[1];
    const float* lsph   = (const float*)d_in[2];
    const float* wsph   = (const float*)d_in[3];
    const float* weight = (const float*)d_in[4];
    float* out = (float*)d_out;

    const int N = out_size; // 1024
    pcc_kernel<<<N, 256, 0, stream>>>(pos, rot, lsph, wsph, weight, out);
}

// Round 13
// 11.794 us; speedup vs baseline: 1.5375x; 1.1080x over previous
//
#include <hip/hip_runtime.h>

// PrimitiveCollisionCost: B=16 H=64 L=12 S=8 W=256, N = B*H = 1024
// One block (256 thr) per n.
// Phase 1: threads 0..95 compute world-frame centers; store coords DUPLICATED
//          ({cx,cx},{cy,cy},{cz,cz},{|c|2+eps,|c|2+eps}) so phase 2 reads
//          VOP3P-ready broadcast pairs straight from LDS (2x ds_read_b128).
//          eps=1e-4 folded into |c|2 guards sqrt against tiny negative d2
//          (cancellation) with zero phase-2 instructions; dist bias <= 5e-3
//          worst case vs 0.129 threshold.
// Phase 2: wave w owns links 3w..3w+2; lane owns 4 world spheres packed as
//          2 pairs. dist^2 via quadratic form d2 = (|c|2+|w|2) - 2 c.w in
//          v_pk_add_f32 / v_pk_fma_f32.

#define NL 12
#define NS 8

typedef float v2f __attribute__((ext_vector_type(2)));

__device__ __forceinline__ float fast_sqrtf(float x) {
    return __builtin_amdgcn_sqrtf(x);   // single v_sqrt_f32 (~1 ulp)
}

__device__ __forceinline__ v2f pk_add(v2f a, v2f b) {
    v2f d;
    asm("v_pk_add_f32 %0, %1, %2" : "=v"(d) : "v"(a), "v"(b));
    return d;
}
__device__ __forceinline__ void pk_fma(v2f& acc, v2f a, v2f b) {
    asm("v_pk_fma_f32 %0, %1, %2, %0" : "+v"(acc) : "v"(a), "v"(b));
}

struct alignas(16) Cen { v2f cx, cy, cz, c2; };   // 32 B, halves duplicated

__global__ __launch_bounds__(256) void pcc_kernel(
    const float* __restrict__ pos,    // (N, L, 3)
    const float* __restrict__ rot,    // (N, L, 9)
    const float* __restrict__ lsph,   // (L, S, 4)
    const float* __restrict__ wsph,   // (W, 4)
    const float* __restrict__ weight, // scalar
    float* __restrict__ out)          // (N)
{
    const int n    = blockIdx.x;
    const int tid  = threadIdx.x;
    const int lane = tid & 63;
    const int wave = tid >> 6;   // 0..3, wave w owns links 3w..3w+2

    __shared__ Cen   cdup[NL * NS];
    __shared__ float rrs[NL * NS];
    __shared__ float partial[4];

    // ---- Phase 1: 96 threads compute 96 centers (once per block) ----
    if (tid < NL * NS) {
        const int l = tid >> 3;               // tid = l*8 + s
        const float* r = rot + ((size_t)n * NL + l) * 9;
        const float* p = pos + ((size_t)n * NL + l) * 3;
        const float4 ls = reinterpret_cast<const float4*>(lsph)[tid];
        const float cx = r[0]*ls.x + r[1]*ls.y + r[2]*ls.z + p[0];
        const float cy = r[3]*ls.x + r[4]*ls.y + r[5]*ls.z + p[1];
        const float cz = r[6]*ls.x + r[7]*ls.y + r[8]*ls.z + p[2];
        const float c2 = cx*cx + cy*cy + cz*cz + 1e-4f;  // eps: sqrt NaN guard
        Cen c;
        c.cx = (v2f){cx, cx};
        c.cy = (v2f){cy, cy};
        c.cz = (v2f){cz, cz};
        c.c2 = (v2f){c2, c2};
        cdup[tid] = c;
        rrs[tid]  = ls.w;
    }

    // 4 world spheres per lane, packed as pairs A=(s0,s1), B=(s2,s3):
    // nw* = -2*w*, q = |w|^2.
    const float4* wsph4 = reinterpret_cast<const float4*>(wsph);
    const float4 ws0 = wsph4[lane];
    const float4 ws1 = wsph4[lane + 64];
    const float4 ws2 = wsph4[lane + 128];
    const float4 ws3 = wsph4[lane + 192];
    const v2f nwxA = {-2.f*ws0.x, -2.f*ws1.x}, nwyA = {-2.f*ws0.y, -2.f*ws1.y}, nwzA = {-2.f*ws0.z, -2.f*ws1.z};
    const v2f nwxB = {-2.f*ws2.x, -2.f*ws3.x}, nwyB = {-2.f*ws2.y, -2.f*ws3.y}, nwzB = {-2.f*ws2.z, -2.f*ws3.z};
    const v2f qA = {ws0.x*ws0.x + ws0.y*ws0.y + ws0.z*ws0.z,
                    ws1.x*ws1.x + ws1.y*ws1.y + ws1.z*ws1.z};
    const v2f qB = {ws2.x*ws2.x + ws2.y*ws2.y + ws2.z*ws2.z,
                    ws3.x*ws3.x + ws3.y*ws3.y + ws3.z*ws3.z};
    const float wr0 = ws0.w, wr1 = ws1.w, wr2 = ws2.w, wr3 = ws3.w;

    __syncthreads();

    // ---- Phase 2: packed quadratic-form distances ----
    float m[3];
    m[0] = m[1] = m[2] = -1e30f;
    const Cen*   base  = &cdup[wave * 24];
    const float* baser = &rrs[wave * 24];

#pragma unroll
    for (int i = 0; i < 24; ++i) {
        const Cen c = base[i];                // wave-uniform ds_read_b128 x2

        v2f dA = pk_add(qA, c.c2);            // |w|^2 + |c|^2 + eps
        v2f dB = pk_add(qB, c.c2);
        pk_fma(dA, c.cx, nwxA);               // - 2 c.w
        pk_fma(dB, c.cx, nwxB);
        pk_fma(dA, c.cy, nwyA);
        pk_fma(dB, c.cy, nwyB);
        pk_fma(dA, c.cz, nwzA);
        pk_fma(dB, c.cz, nwzB);

        const float g0 = wr0 - fast_sqrtf(dA.x);
        const float g1 = wr1 - fast_sqrtf(dA.y);
        const float g2 = wr2 - fast_sqrtf(dB.x);
        const float g3 = wr3 - fast_sqrtf(dB.y);

        // ((g0 v g1) v g2) v g3 -> v_max3_f32 + v_max_f32
        const float t = fmaxf(fmaxf(fmaxf(g0, g1), g2), g3);
        const int li = i >> 3;                // compile-time after unroll
        m[li] = fmaxf(m[li], t + baser[i]);
    }

    // Three interleaved 64-lane max butterflies.
#pragma unroll
    for (int off = 1; off < 64; off <<= 1) {
        m[0] = fmaxf(m[0], __shfl_xor(m[0], off));
        m[1] = fmaxf(m[1], __shfl_xor(m[1], off));
        m[2] = fmaxf(m[2], __shfl_xor(m[2], off));
    }

    // d = clip(m + 0.1, 0, 0.2) / 0.25  (== clamp * 4)
    const float acc = fminf(fmaxf(m[0] + 0.1f, 0.0f), 0.2f) * 4.0f
                    + fminf(fmaxf(m[1] + 0.1f, 0.0f), 0.2f) * 4.0f
                    + fminf(fmaxf(m[2] + 0.1f, 0.0f), 0.2f) * 4.0f;

    if (lane == 0) partial[wave] = acc;
    __syncthreads();
    if (tid == 0)
        out[n] = weight[0] * (partial[0] + partial[1] + partial[2] + partial[3]);
}

extern "C" void kernel_launch(void* const* d_in, const int* in_sizes, int n_in,
                              void* d_out, int out_size, void* d_ws, size_t ws_size,
                              hipStream_t stream) {
    const float* pos    = (const float*)d_in[0];
    const float* rot    = (const float*)d_in[1];
    const float* lsph   = (const float*)d_in[2];
    const float* wsph   = (const float*)d_in[3];
    const float* weight = (const float*)d_in[4];
    float* out = (float*)d_out;

    const int N = out_size; // 1024
    pcc_kernel<<<N, 256, 0, stream>>>(pos, rot, lsph, wsph, weight, out);
}